// Round 6
// baseline (484.168 us; speedup 1.0000x reference)
//
#include <hip/hip_runtime.h>

#define TT 1024
#define BB 2048
#define K1 8
#define L2E2 2.8853900817779268f  // 2*log2(e)

// DPP helpers ----------------------------------------------------------------
template <int CTRL>
__device__ __forceinline__ float dpp_add(float x) {
  int y = __builtin_amdgcn_update_dpp(0, __float_as_int(x), CTRL, 0xF, 0xF, true);
  return x + __int_as_float(y);
}
// Two interleaved 16-lane-row sums (independent chains fill hazard slots).
__device__ __forceinline__ void sum16x2(float& a, float& b) {
  a = dpp_add<0xB1>(a);  b = dpp_add<0xB1>(b);   // quad_perm xor1
  a = dpp_add<0x4E>(a);  b = dpp_add<0x4E>(b);   // quad_perm xor2
  a = dpp_add<0x141>(a); b = dpp_add<0x141>(b);  // row_half_mirror
  a = dpp_add<0x140>(a); b = dpp_add<0x140>(b);  // row_mirror
}
// ROW_BCAST15: row r gets last lane of row r-1 (row0 -> 0).
__device__ __forceinline__ float bcast15(float x) {
  return __int_as_float(
      __builtin_amdgcn_update_dpp(0, __float_as_int(x), 0x142, 0xF, 0xF, true));
}
__device__ __forceinline__ float rdlane(float x, int l) {
  return __int_as_float(__builtin_amdgcn_readlane(__float_as_int(x), l));
}

// ---------------------------------------------------------------------------
// Phase 1: sequential RK4 scan. TWO elements per 64-lane wave, interleaved in
// the instruction stream (ILP replaces TLP: 1024 waves = 1 wave/SIMD; the
// second element's chain fills DPP-hazard and transcendental-latency slots).
// Lane rows: row0=NN1/A, row1=NN2/B, row2=NN3/C, row3=dummy(NN3 dup).
// Per stage per element: eval (5), sum16 (4 DPP), ONE bcast15 (row1<-P1,
// row2<-P2), ONE readlane (P3, lane 32), combine (4 fma w/ per-lane coeffs):
//   row0: KA = -0.1A + (0.2-C1) + 0.1u - P1(own)
//   row1: KB = -0.1B + cbC - 3*P2(own) + (5/3)*P1(m) + P3(readlane)
//   row2: KC = -0.1C + ccC -   P3(own) +       P2(m)
__global__ __launch_bounds__(256) void phase1_kernel(
    const float* __restrict__ useq, const float* __restrict__ x0,
    const float* __restrict__ r1W0, const float* __restrict__ r1b0,
    const float* __restrict__ r1W1, const float* __restrict__ r1b1,
    const float* __restrict__ r2W0, const float* __restrict__ r2b0,
    const float* __restrict__ r2W1, const float* __restrict__ r2b1,
    const float* __restrict__ r3W0, const float* __restrict__ r3b0,
    const float* __restrict__ r3W1, const float* __restrict__ r3b1,
    float* __restrict__ out) {
  const int lane = threadIdx.x & 63;
  const int row = lane >> 4;
  const int j = lane & 15;
  const int gw =
      __builtin_amdgcn_readfirstlane(blockIdx.x * 4 + (threadIdx.x >> 6));
  const int e0 = gw * 2, e1 = e0 + 1;

  const float* W0p = (row == 0) ? r1W0 : (row == 1) ? r2W0 : r3W0;
  const float* b0p = (row == 0) ? r1b0 : (row == 1) ? r2b0 : r3b0;
  const float* W1p = (row == 0) ? r1W1 : (row == 1) ? r2W1 : r3W1;

  const float w0s = W0p[j] * L2E2;
  const float b0s = b0p[j] * L2E2;
  const float wn = -2.0f * W1p[j];

  // C_i = b1_i + sum_j W1_i[j]  (uniform, init-only).
  float C1 = r1b1[0], C2 = r2b1[0], C3 = r3b1[0];
  for (int q = 0; q < 16; ++q) {
    C1 += r1W1[q]; C2 += r2W1[q]; C3 += r3W1[q];
  }
  const float caC = 0.2f - C1;
  const float cbC = -1.0f / 6.0f + (5.0f / 3.0f) * C1 - 3.0f * C2 + C3;
  const float ccC = -1.0f / 6.0f + C2 - C3;

  // Per-lane combine coefficients.
  const float cstBase = (row == 0) ? caC : (row == 1) ? cbC : ccC;
  const float uco = (row == 0) ? 0.1f : 0.0f;
  const float aOwn = (row == 1) ? -3.0f : (row == 3) ? 0.0f : -1.0f;
  const float aM = (row == 1) ? (5.0f / 3.0f) : (row == 2) ? 1.0f : 0.0f;
  const float aR = (row == 1) ? 1.0f : 0.0f;

  float S0 = x0[e0 * 15 + ((row < 3) ? row : 2)];
  float S1 = x0[e1 * 15 + ((row < 3) ? row : 2)];

  const float* up0 = useq + e0 * TT;
  const float* up1 = useq + e1 * TT;
  float* op0 = out + (size_t)e0 * TT * 4;
  float* op1 = out + (size_t)e1 * TT * 4;

#define STAGE2(X0_, X1_, K0_, K1_)                                       \
  {                                                                      \
    float pa0 = fmaf(w0s, (X0_), b0s);                                   \
    float pa1 = fmaf(w0s, (X1_), b0s);                                   \
    float ex0 = __builtin_amdgcn_exp2f(pa0);                             \
    float ex1 = __builtin_amdgcn_exp2f(pa1);                             \
    float rv0 = __builtin_amdgcn_rcpf(ex0 + 1.0f);                       \
    float rv1 = __builtin_amdgcn_rcpf(ex1 + 1.0f);                       \
    float q0 = wn * rv0;                                                 \
    float q1 = wn * rv1;                                                 \
    sum16x2(q0, q1);                                                     \
    float m0 = bcast15(q0);                                              \
    float m1 = bcast15(q1);                                              \
    float P30 = rdlane(q0, 32);                                          \
    float P31 = rdlane(q1, 32);                                          \
    float t0_ = fmaf(-0.1f, (X0_), cst0);                                \
    float t1_ = fmaf(-0.1f, (X1_), cst1);                                \
    t0_ = fmaf(aOwn, q0, t0_);                                           \
    t1_ = fmaf(aOwn, q1, t1_);                                           \
    t0_ = fmaf(aM, m0, t0_);                                             \
    t1_ = fmaf(aM, m1, t1_);                                             \
    K0_ = fmaf(aR, P30, t0_);                                            \
    K1_ = fmaf(aR, P31, t1_);                                            \
  }

#define STEP2(U0_, U1_, SA_, SB_)                                        \
  {                                                                      \
    const float cst0 = fmaf(uco, (U0_), cstBase);                        \
    const float cst1 = fmaf(uco, (U1_), cstBase);                        \
    SA_ = S0; SB_ = S1;                                                  \
    float k10, k11, k20, k21, k30, k31, k40, k41;                        \
    STAGE2(S0, S1, k10, k11)                                             \
    float n0 = fmaf(0.5f, k10, S0), n1 = fmaf(0.5f, k11, S1);            \
    STAGE2(n0, n1, k20, k21)                                             \
    n0 = fmaf(0.5f, k20, S0); n1 = fmaf(0.5f, k21, S1);                  \
    STAGE2(n0, n1, k30, k31)                                             \
    n0 = S0 + k30; n1 = S1 + k31;                                        \
    STAGE2(n0, n1, k40, k41)                                             \
    S0 = fmaf(1.0f / 6.0f, fmaf(2.0f, k20 + k30, k10) + k40, S0);        \
    S1 = fmaf(1.0f / 6.0f, fmaf(2.0f, k21 + k31, k11) + k41, S1);        \
  }

  float ua0, ua1, ua2, ua3, ua4, ua5, ua6, ua7;
  float ub0, ub1, ub2, ub3, ub4, ub5, ub6, ub7;
  {
    float4 a = *(const float4*)(up0);
    float4 b = *(const float4*)(up0 + 4);
    float4 c = *(const float4*)(up1);
    float4 d = *(const float4*)(up1 + 4);
    ua0 = a.x; ua1 = a.y; ua2 = a.z; ua3 = a.w;
    ua4 = b.x; ua5 = b.y; ua6 = b.z; ua7 = b.w;
    ub0 = c.x; ub1 = c.y; ub2 = c.z; ub3 = c.w;
    ub4 = d.x; ub5 = d.y; ub6 = d.z; ub7 = d.w;
  }

  for (int t0 = 0; t0 < TT; t0 += K1) {
    const int tn = (t0 + K1 <= TT - K1) ? (t0 + K1) : (TT - K1);
    const float4 na = *(const float4*)(up0 + tn);
    const float4 nb = *(const float4*)(up0 + tn + 4);
    const float4 nc = *(const float4*)(up1 + tn);
    const float4 nd = *(const float4*)(up1 + tn + 4);

    float sA0, sA1, sA2, sA3, sA4, sA5, sA6, sA7;
    float sB0, sB1, sB2, sB3, sB4, sB5, sB6, sB7;
    STEP2(ua0, ub0, sA0, sB0)
    STEP2(ua1, ub1, sA1, sB1)
    STEP2(ua2, ub2, sA2, sB2)
    STEP2(ua3, ub3, sA3, sB3)
    STEP2(ua4, ub4, sA4, sB4)
    STEP2(ua5, ub5, sA5, sB5)
    STEP2(ua6, ub6, sA6, sB6)
    STEP2(ua7, ub7, sA7, sB7)

    // Batched stores: lanes 0/16/32 write components 0/1/2 for both elements.
    if (j == 0 && row < 3) {
      float* p0 = op0 + t0 * 4 + row;
      p0[0] = sA0;  p0[4] = sA1;  p0[8] = sA2;  p0[12] = sA3;
      p0[16] = sA4; p0[20] = sA5; p0[24] = sA6; p0[28] = sA7;
      float* p1 = op1 + t0 * 4 + row;
      p1[0] = sB0;  p1[4] = sB1;  p1[8] = sB2;  p1[12] = sB3;
      p1[16] = sB4; p1[20] = sB5; p1[24] = sB6; p1[28] = sB7;
    }

    ua0 = na.x; ua1 = na.y; ua2 = na.z; ua3 = na.w;
    ua4 = nb.x; ua5 = nb.y; ua6 = nb.z; ua7 = nb.w;
    ub0 = nc.x; ub1 = nc.y; ub2 = nc.z; ub3 = nc.w;
    ub4 = nd.x; ub5 = nd.y; ub6 = nd.z; ub7 = nd.w;
  }
#undef STEP2
#undef STAGE2
}

// ---------------------------------------------------------------------------
// Phase 2: out[b,t,3] = estC(z_t). One block per batch row, 4 samples/thread.
// z gathered as 4x global_load_dwordx4 (coalesced; reads the not-yet-written
// [3] slot harmlessly). Weights broadcast from LDS as same-address float4.
__global__ __launch_bounds__(256) void phase2_kernel(
    const float* __restrict__ useq, const float* __restrict__ x0,
    const float* __restrict__ W0, const float* __restrict__ b0,
    const float* __restrict__ W1, const float* __restrict__ b1p,
    float* __restrict__ out) {
  __shared__ float4 wrow[32][4];  // {w0..3},{w4..7},{w8..11},{b0s,w1n,-,-}
  for (int idx = threadIdx.x; idx < 512; idx += 256) {
    const int h = idx >> 4, r = idx & 15;
    float v = 0.0f;
    if (r < 12) v = W0[r * 32 + h] * L2E2;
    else if (r == 12) v = b0[h] * L2E2;
    else if (r == 13) v = -2.0f * W1[h];
    ((float*)&wrow[h][0])[r] = v;
  }
  __syncthreads();

  float base = b1p[0];
#pragma unroll
  for (int h = 0; h < 32; ++h) base += W1[h];  // uniform s_loads, cached

  const int b = blockIdx.x;
  const float* xrow = x0 + b * 15;

  float z[4][12];
#pragma unroll
  for (int k = 0; k < 4; ++k) {
    const int t = k * 256 + (int)threadIdx.x;
    const int g = (b << 10) + t;
    if (t >= 4) {
      const float* pb = out + (size_t)(g - 4) * 4;
      const float4 h0 = *(const float4*)(pb);
      const float4 h1 = *(const float4*)(pb + 4);
      const float4 h2 = *(const float4*)(pb + 8);
      const float4 h3 = *(const float4*)(pb + 12);
      z[k][0] = h0.x; z[k][1] = h0.y;
      z[k][2] = h1.x; z[k][3] = h1.y;
      z[k][4] = h2.x; z[k][5] = h2.y;
      z[k][6] = h3.x; z[k][7] = h3.y;
      const float* pu = useq + g;
#pragma unroll
      for (int i = 0; i < 4; ++i) z[k][8 + i] = pu[i - 4];
    } else {
#pragma unroll
      for (int i = 0; i < 4; ++i) {
        const int s4 = t - 4 + i;
        const float* py = (s4 >= 0) ? (out + ((size_t)(b << 10) + s4) * 4)
                                    : (xrow + 3 + 2 * (i + t));
        z[k][2 * i] = py[0];
        z[k][2 * i + 1] = py[1];
        const float* pu = (s4 >= 0) ? (useq + (b << 10) + s4)
                                    : (xrow + 11 + i + t);
        z[k][8 + i] = pu[0];
      }
    }
  }

  float ov0 = base, ov1 = base, ov2 = base, ov3 = base;
#pragma unroll
  for (int h = 0; h < 32; ++h) {
    const float4 wa = wrow[h][0];
    const float4 wb = wrow[h][1];
    const float4 wc = wrow[h][2];
    const float4 wd = wrow[h][3];
#define ACC(OV, ZZ)                                                       \
  {                                                                       \
    float a = wd.x;                                                       \
    a = fmaf(ZZ[0], wa.x, a);  a = fmaf(ZZ[1], wa.y, a);                  \
    a = fmaf(ZZ[2], wa.z, a);  a = fmaf(ZZ[3], wa.w, a);                  \
    a = fmaf(ZZ[4], wb.x, a);  a = fmaf(ZZ[5], wb.y, a);                  \
    a = fmaf(ZZ[6], wb.z, a);  a = fmaf(ZZ[7], wb.w, a);                  \
    a = fmaf(ZZ[8], wc.x, a);  a = fmaf(ZZ[9], wc.y, a);                  \
    a = fmaf(ZZ[10], wc.z, a); a = fmaf(ZZ[11], wc.w, a);                 \
    const float r = __builtin_amdgcn_rcpf(__builtin_amdgcn_exp2f(a) + 1.0f); \
    OV = fmaf(wd.y, r, OV);                                               \
  }
    ACC(ov0, z[0])
    ACC(ov1, z[1])
    ACC(ov2, z[2])
    ACC(ov3, z[3])
#undef ACC
  }

  const size_t gb = (size_t)(b << 10) + threadIdx.x;
  out[(gb + 0) * 4 + 3] = ov0;
  out[(gb + 256) * 4 + 3] = ov1;
  out[(gb + 512) * 4 + 3] = ov2;
  out[(gb + 768) * 4 + 3] = ov3;
}

// ---------------------------------------------------------------------------
extern "C" void kernel_launch(void* const* d_in, const int* in_sizes, int n_in,
                              void* d_out, int out_size, void* d_ws,
                              size_t ws_size, hipStream_t stream) {
  const float* useq = (const float*)d_in[0];
  const float* x0 = (const float*)d_in[1];
  float* out = (float*)d_out;

  phase1_kernel<<<BB / 8, 256, 0, stream>>>(
      useq, x0,
      (const float*)d_in[2], (const float*)d_in[3], (const float*)d_in[4],
      (const float*)d_in[5], (const float*)d_in[6], (const float*)d_in[7],
      (const float*)d_in[8], (const float*)d_in[9], (const float*)d_in[10],
      (const float*)d_in[11], (const float*)d_in[12], (const float*)d_in[13],
      out);

  phase2_kernel<<<BB, 256, 0, stream>>>(
      useq, x0, (const float*)d_in[14], (const float*)d_in[15],
      (const float*)d_in[16], (const float*)d_in[17], out);
}